// Round 1
// baseline (197.897 us; speedup 1.0000x reference)
//
#include <hip/hip_runtime.h>
#include <hip/hip_bf16.h>
#include <math.h>

#define B_ 32
#define N_ 4096
#define C_ 64
#define H_ 256
#define P_ 8

typedef short bf16x8 __attribute__((ext_vector_type(8)));
typedef float f32x4 __attribute__((ext_vector_type(4)));

__device__ __forceinline__ unsigned short f2bf(float f) {
    union { float f; unsigned int u; } v; v.f = f;
    unsigned int r = v.u + 0x7FFFu + ((v.u >> 16) & 1u);
    return (unsigned short)(r >> 16);
}

// ---------------- pool: pooled[b][c] = sum_n u[b][n][c] ----------------
__global__ void pool_kernel(const float* __restrict__ u, float* __restrict__ pooled) {
    int b = blockIdx.y, chunk = blockIdx.x;
    int tid = threadIdx.x, c = tid & 63, rg = tid >> 6;
    const float* base = u + ((size_t)b * N_ + (size_t)chunk * 128) * C_;
    float s = 0.f;
    #pragma unroll 4
    for (int i = 0; i < 32; ++i) s += base[(i * 4 + rg) * C_ + c];
    __shared__ float red[4][64];
    red[rg][c] = s;
    __syncthreads();
    if (tid < 64) {
        float t = red[0][tid] + red[1][tid] + red[2][tid] + red[3][tid];
        atomicAdd(&pooled[b * C_ + tid], t);
    }
}

// ---------------- router: logits -> top2 -> softmax weights ----------------
__global__ void router_kernel(const float* __restrict__ pooled, const float* __restrict__ Wr,
                              const float* __restrict__ br, float4* __restrict__ route) {
    int b = threadIdx.x;
    if (b >= B_) return;
    float lg[P_];
    for (int p = 0; p < P_; ++p) {
        float s = br[p];
        for (int c = 0; c < C_; ++c) s += pooled[b * C_ + c] * (1.0f / N_) * Wr[c * P_ + p];
        lg[p] = s;
    }
    int i0 = 0;
    for (int p = 1; p < P_; ++p) if (lg[p] > lg[i0]) i0 = p;   // strict > : lowest index on tie
    int i1 = (i0 == 0) ? 1 : 0;
    for (int p = 0; p < P_; ++p) if (p != i0 && lg[p] > lg[i1]) i1 = p;
    float e1 = expf(lg[i1] - lg[i0]);
    float w0 = 1.f / (1.f + e1), w1 = e1 / (1.f + e1);
    route[b] = make_float4(w0, w1, __int_as_float(i0), __int_as_float(i1));
}

// ---------------- prep: W1 (P,C,H) -> W1T bf16 [e][h][c]; W2 (P,H,C) -> W2T bf16 [e][c][h]
__global__ void prep_kernel(const float* __restrict__ W1, const float* __restrict__ W2,
                            unsigned short* __restrict__ W1T, unsigned short* __restrict__ W2T) {
    int idx = blockIdx.x * 256 + threadIdx.x;   // enumerate [e][h][c]
    int e = idx >> 14, rem = idx & 16383, h = rem >> 6, c = rem & 63;
    W1T[idx] = f2bf(W1[(e << 14) + c * H_ + h]);          // W1T[e][h][c] = W1[e][c][h]
    W2T[(e << 14) + c * H_ + h] = f2bf(W2[idx]);          // W2T[e][c][h] = W2[e][h][c]
}

// ---------------- main fused MoE-MLP ----------------
// grid (N/64, B), 256 threads (4 waves). Waves split columns so each expert's
// weights are fetched from L2 exactly once per block.
__global__ __launch_bounds__(256, 2)
void moe_main(const float* __restrict__ u, const float* __restrict__ b1,
              const float* __restrict__ b2, const unsigned short* __restrict__ W1T,
              const unsigned short* __restrict__ W2T, const float4* __restrict__ route,
              float* __restrict__ out) {
    __shared__ float uF[64][68];                 // f32 u tile (exact residual)
    __shared__ unsigned short uA[64][72];        // bf16 u tile (MFMA A), padded stride
    __shared__ unsigned short h1s[64][264];      // bf16 h1 tile, padded stride

    const int b = blockIdx.y;
    const int n0 = blockIdx.x * 64;
    const int tid = threadIdx.x;

    // ---- stage u tile (64 rows x 64 c), f32 + bf16 ----
    const float4* up = (const float4*)(u + ((size_t)b * N_ + n0) * C_);
    #pragma unroll
    for (int i = 0; i < 4; ++i) {
        int idx = tid + 256 * i;
        int row = idx >> 4, c4 = idx & 15;
        float4 v = up[idx];
        *(float4*)&uF[row][c4 * 4] = v;
        ushort4 hv = make_ushort4(f2bf(v.x), f2bf(v.y), f2bf(v.z), f2bf(v.w));
        *(ushort4*)&uA[row][c4 * 4] = hv;
    }

    float4 rd = route[b];
    float wk2[2] = { rd.x, rd.y };
    int eidx[2] = { __float_as_int(rd.z), __float_as_int(rd.w) };

    const int lane = tid & 63, w = tid >> 6;
    const int r = lane & 15, g = lane >> 4;

    __syncthreads();

    float accOut[4][4];
    #pragma unroll
    for (int rt = 0; rt < 4; ++rt)
        #pragma unroll
        for (int j = 0; j < 4; ++j) accOut[rt][j] = 0.f;

    for (int ke = 0; ke < 2; ++ke) {
        const int e = eidx[ke];
        const float wk = wk2[ke];
        const unsigned short* w1e = W1T + (e << 14);
        const unsigned short* w2e = W2T + (e << 14);

        // ---- GEMM1: h1[64][256] = u(64x64) @ W1e(64x256); wave w owns h-cols [w*64, w*64+64)
        f32x4 acc1[4][4];   // [ct][rt]
        #pragma unroll
        for (int ct = 0; ct < 4; ++ct)
            #pragma unroll
            for (int rt = 0; rt < 4; ++rt)
                #pragma unroll
                for (int q = 0; q < 4; ++q) acc1[ct][rt][q] = 0.f;

        #pragma unroll
        for (int ks = 0; ks < 2; ++ks) {
            bf16x8 a[4];
            #pragma unroll
            for (int rt = 0; rt < 4; ++rt)
                a[rt] = *(const bf16x8*)&uA[rt * 16 + r][ks * 32 + g * 8];
            #pragma unroll
            for (int ct = 0; ct < 4; ++ct) {
                int col = w * 64 + ct * 16 + r;
                bf16x8 bf = *(const bf16x8*)(w1e + col * C_ + ks * 32 + g * 8);
                #pragma unroll
                for (int rt = 0; rt < 4; ++rt)
                    acc1[ct][rt] = __builtin_amdgcn_mfma_f32_16x16x32_bf16(a[rt], bf, acc1[ct][rt], 0, 0, 0);
            }
        }
        // ---- bias + erf-GELU + store h1 (bf16) ----
        #pragma unroll
        for (int ct = 0; ct < 4; ++ct) {
            int col = w * 64 + ct * 16 + r;
            float bias = b1[e * H_ + col];
            #pragma unroll
            for (int rt = 0; rt < 4; ++rt) {
                #pragma unroll
                for (int j = 0; j < 4; ++j) {
                    float x = acc1[ct][rt][j] + bias;
                    float gl = 0.5f * x * (1.f + erff(x * 0.70710678118654752f));
                    h1s[rt * 16 + g * 4 + j][col] = f2bf(gl);
                }
            }
        }
        __syncthreads();

        // ---- GEMM2: delta[64][64] = h1(64x256) @ W2e(256x64); wave w owns c-cols [w*16, w*16+16)
        f32x4 acc2[4];
        #pragma unroll
        for (int rt = 0; rt < 4; ++rt)
            #pragma unroll
            for (int q = 0; q < 4; ++q) acc2[rt][q] = 0.f;
        const int c = w * 16 + r;
        #pragma unroll
        for (int ks2 = 0; ks2 < 8; ++ks2) {
            bf16x8 bf2 = *(const bf16x8*)(w2e + c * H_ + ks2 * 32 + g * 8);
            #pragma unroll
            for (int rt = 0; rt < 4; ++rt) {
                bf16x8 a2 = *(const bf16x8*)&h1s[rt * 16 + r][ks2 * 32 + g * 8];
                acc2[rt] = __builtin_amdgcn_mfma_f32_16x16x32_bf16(a2, bf2, acc2[rt], 0, 0, 0);
            }
        }
        float b2v = b2[e * C_ + c];
        #pragma unroll
        for (int rt = 0; rt < 4; ++rt)
            #pragma unroll
            for (int j = 0; j < 4; ++j)
                accOut[rt][j] += wk * (acc2[rt][j] + b2v);
        __syncthreads();   // protect h1s before next expert overwrites
    }

    // ---- epilogue: out = u + delta_sum ----
    const int cc = w * 16 + r;
    #pragma unroll
    for (int rt = 0; rt < 4; ++rt) {
        #pragma unroll
        for (int j = 0; j < 4; ++j) {
            int row = rt * 16 + g * 4 + j;
            out[((size_t)b * N_ + n0 + row) * C_ + cc] = uF[row][cc] + accOut[rt][j];
        }
    }
}

extern "C" void kernel_launch(void* const* d_in, const int* in_sizes, int n_in,
                              void* d_out, int out_size, void* d_ws, size_t ws_size,
                              hipStream_t stream) {
    const float* u  = (const float*)d_in[0];
    const float* W1 = (const float*)d_in[1];
    const float* b1 = (const float*)d_in[2];
    const float* W2 = (const float*)d_in[3];
    const float* b2 = (const float*)d_in[4];
    const float* Wr = (const float*)d_in[5];
    const float* br = (const float*)d_in[6];
    float* out = (float*)d_out;

    char* ws = (char*)d_ws;
    float* pooled = (float*)ws;                              // 2048 f32 = 8 KB
    float4* route = (float4*)(ws + 8192);                    // 32 x 16 B
    unsigned short* W1T = (unsigned short*)(ws + 16384);     // 256 KB
    unsigned short* W2T = (unsigned short*)(ws + 16384 + 262144); // 256 KB

    hipMemsetAsync(pooled, 0, 2048 * sizeof(float), stream);
    prep_kernel<<<512, 256, 0, stream>>>(W1, W2, W1T, W2T);
    pool_kernel<<<dim3(32, 32), 256, 0, stream>>>(u, pooled);
    router_kernel<<<1, 64, 0, stream>>>(pooled, Wr, br, route);
    moe_main<<<dim3(64, 32), 256, 0, stream>>>(u, b1, b2, W1T, W2T, route, out);
}

// Round 3
// 192.016 us; speedup vs baseline: 1.0306x; 1.0306x over previous
//
#include <hip/hip_runtime.h>
#include <hip/hip_bf16.h>
#include <math.h>

#define B_ 32
#define N_ 4096
#define C_ 64
#define H_ 256
#define P_ 8

typedef short bf16x8 __attribute__((ext_vector_type(8)));
typedef float f32x4 __attribute__((ext_vector_type(4)));

__device__ __forceinline__ unsigned short f2bf(float f) {
    union { float f; unsigned int u; } v; v.f = f;
    unsigned int r = v.u + 0x7FFFu + ((v.u >> 16) & 1u);
    return (unsigned short)(r >> 16);
}

// tanh-form GELU using hardware exp; |dev from erf-gelu| <= ~7e-4
__device__ __forceinline__ float gelu_f(float x) {
    float x2 = x * x;
    float y = x * fmaf(0.044715f * 0.7978845608028654f, x2, 0.7978845608028654f);
    float e = __expf(2.f * y);                 // v_exp_f32
    float t = 1.f - 2.f / (e + 1.f);           // tanh(y)
    return 0.5f * x * (1.f + t);
}

// ---------------- fused prep (blocks 0..511) + pool (blocks 512..1535) ----------------
// prep: W1 (P,C,H) -> W1T bf16 [e][h][c]; W2 (P,H,C) -> W2T bf16 [e][c][h]
// pool: pooled[b][c] = sum_n u[b][n][c]  (atomic partial sums)
__global__ void prep_pool_kernel(const float* __restrict__ W1, const float* __restrict__ W2,
                                 const float* __restrict__ u,
                                 unsigned short* __restrict__ W1T, unsigned short* __restrict__ W2T,
                                 float* __restrict__ pooled) {
    int bid = blockIdx.x, tid = threadIdx.x;
    if (bid < 512) {
        int idx = bid * 256 + tid;              // enumerate [e][h][c]
        int e = idx >> 14, rem = idx & 16383, h = rem >> 6, c = rem & 63;
        W1T[idx] = f2bf(W1[(e << 14) + c * H_ + h]);      // W1T[e][h][c] = W1[e][c][h]
        W2T[(e << 14) + c * H_ + h] = f2bf(W2[idx]);      // W2T[e][c][h] = W2[e][h][c]
        return;
    }
    int pb = bid - 512;
    int b = pb >> 5, chunk = pb & 31;
    int c = tid & 63, rg = tid >> 6;
    const float* base = u + ((size_t)b * N_ + (size_t)chunk * 128) * C_;
    float s = 0.f;
    #pragma unroll 4
    for (int i = 0; i < 32; ++i) s += base[(i * 4 + rg) * C_ + c];
    __shared__ float red[4][64];
    red[rg][c] = s;
    __syncthreads();
    if (tid < 64) {
        float t = red[0][tid] + red[1][tid] + red[2][tid] + red[3][tid];
        atomicAdd(&pooled[b * C_ + tid], t);
    }
}

// ---------------- main fused router + MoE-MLP ----------------
// grid (N/64, B), 256 threads (4 waves). Router computed per-block (uniform, ~300 cyc).
// GEMM1 computes h1^T via swapped mfma operands so h1 stores are packed b64 and
// GEMM2's A-fragment reads are b128.
__global__ __launch_bounds__(256, 3)
void moe_main(const float* __restrict__ u, const float* __restrict__ b1,
              const float* __restrict__ b2, const unsigned short* __restrict__ W1T,
              const unsigned short* __restrict__ W2T, const float* __restrict__ pooled,
              const float* __restrict__ Wr, const float* __restrict__ br,
              float* __restrict__ out) {
    __shared__ __align__(16) unsigned short uA[64][72];     // bf16 u tile (B-fragment source)
    __shared__ __align__(16) unsigned short h1s[64][264];   // bf16 h1 tile [n][h], padded
    __shared__ float lgS[8];

    const int b = blockIdx.y;
    const int n0 = blockIdx.x * 64;
    const int tid = threadIdx.x;

    // ---- issue u tile loads (64 rows x 64 c) ----
    const float4* up = (const float4*)(u + ((size_t)b * N_ + n0) * C_);
    float4 v[4];
    #pragma unroll
    for (int i = 0; i < 4; ++i) v[i] = up[tid + 256 * i];

    // ---- router logits (8 threads, overlapped with loads) ----
    if (tid < 8) {
        float s = br[tid];
        const float* pb = pooled + b * C_;
        #pragma unroll
        for (int c = 0; c < C_; ++c) s += pb[c] * (1.0f / N_) * Wr[c * P_ + tid];
        lgS[tid] = s;
    }

    // ---- stage bf16 u tile ----
    #pragma unroll
    for (int i = 0; i < 4; ++i) {
        int idx = tid + 256 * i;
        int row = idx >> 4, c4 = idx & 15;
        ushort4 hv = make_ushort4(f2bf(v[i].x), f2bf(v[i].y), f2bf(v[i].z), f2bf(v[i].w));
        *(ushort4*)&uA[row][c4 * 4] = hv;
    }
    __syncthreads();

    // ---- top-2 + softmax (redundant per-thread, uniform) ----
    float lg[8];
    #pragma unroll
    for (int p = 0; p < 8; ++p) lg[p] = lgS[p];
    int i0 = 0;
    #pragma unroll
    for (int p = 1; p < 8; ++p) if (lg[p] > lg[i0]) i0 = p;   // strict >: lowest idx on tie
    int i1 = (i0 == 0) ? 1 : 0;
    #pragma unroll
    for (int p = 0; p < 8; ++p) if (p != i0 && lg[p] > lg[i1]) i1 = p;
    float e1 = __expf(lg[i1] - lg[i0]);
    float w0r = 1.f / (1.f + e1);
    float wk2[2] = { w0r, e1 * w0r };
    int eidx[2] = { i0, i1 };

    const int lane = tid & 63, w = tid >> 6;
    const int r = lane & 15, g = lane >> 4;

    float accOut[4][4];
    #pragma unroll
    for (int rt = 0; rt < 4; ++rt)
        #pragma unroll
        for (int j = 0; j < 4; ++j) accOut[rt][j] = 0.f;

    for (int ke = 0; ke < 2; ++ke) {
        const int e = eidx[ke];
        const float wk = wk2[ke];
        const unsigned short* w1e = W1T + (e << 14);
        const unsigned short* w2e = W2T + (e << 14);

        // ---- GEMM1 (swapped): h1T tile; A = W1^T (h x c), B = u^T (c x n)
        // D row = h-local (g*4+j), col = n-local (r). Wave w owns h-cols [w*64, w*64+64).
        f32x4 acc1[4][4];   // [ct][rt]
        #pragma unroll
        for (int ct = 0; ct < 4; ++ct)
            #pragma unroll
            for (int rt = 0; rt < 4; ++rt)
                #pragma unroll
                for (int q = 0; q < 4; ++q) acc1[ct][rt][q] = 0.f;

        #pragma unroll
        for (int ks = 0; ks < 2; ++ks) {
            bf16x8 bu[4];
            #pragma unroll
            for (int rt = 0; rt < 4; ++rt)
                bu[rt] = *(const bf16x8*)&uA[rt * 16 + r][ks * 32 + g * 8];
            #pragma unroll
            for (int ct = 0; ct < 4; ++ct) {
                int hrow = w * 64 + ct * 16 + r;
                bf16x8 aw = *(const bf16x8*)(w1e + hrow * C_ + ks * 32 + g * 8);
                #pragma unroll
                for (int rt = 0; rt < 4; ++rt)
                    acc1[ct][rt] = __builtin_amdgcn_mfma_f32_16x16x32_bf16(aw, bu[rt], acc1[ct][rt], 0, 0, 0);
            }
        }

        // ---- bias + GELU + packed h1 store: h1s[n = rt*16+r][h = w*64+ct*16+g*4 + j]
        #pragma unroll
        for (int ct = 0; ct < 4; ++ct) {
            int hbase = w * 64 + ct * 16 + g * 4;
            float4 bias = *(const float4*)(b1 + e * H_ + hbase);
            #pragma unroll
            for (int rt = 0; rt < 4; ++rt) {
                float g0 = gelu_f(acc1[ct][rt][0] + bias.x);
                float g1 = gelu_f(acc1[ct][rt][1] + bias.y);
                float g2 = gelu_f(acc1[ct][rt][2] + bias.z);
                float g3 = gelu_f(acc1[ct][rt][3] + bias.w);
                ushort4 hv = make_ushort4(f2bf(g0), f2bf(g1), f2bf(g2), f2bf(g3));
                *(ushort4*)&h1s[rt * 16 + r][hbase] = hv;
            }
        }
        __syncthreads();

        // ---- GEMM2: delta = h1 (n x h) @ W2 (h x c); wave w owns c-cols [w*16, w*16+16)
        f32x4 acc2[4];
        #pragma unroll
        for (int rt = 0; rt < 4; ++rt)
            #pragma unroll
            for (int q = 0; q < 4; ++q) acc2[rt][q] = 0.f;
        const int c = w * 16 + r;
        #pragma unroll
        for (int ks2 = 0; ks2 < 8; ++ks2) {
            bf16x8 bw = *(const bf16x8*)(w2e + c * H_ + ks2 * 32 + g * 8);
            #pragma unroll
            for (int rt = 0; rt < 4; ++rt) {
                bf16x8 ah = *(const bf16x8*)&h1s[rt * 16 + r][ks2 * 32 + g * 8];
                acc2[rt] = __builtin_amdgcn_mfma_f32_16x16x32_bf16(ah, bw, acc2[rt], 0, 0, 0);
            }
        }
        float b2v = b2[e * C_ + c];
        #pragma unroll
        for (int rt = 0; rt < 4; ++rt)
            #pragma unroll
            for (int j = 0; j < 4; ++j)
                accOut[rt][j] += wk * (acc2[rt][j] + b2v);
        __syncthreads();   // h1s reused by next expert / dS epilogue
    }

    // ---- epilogue: transpose delta through LDS, then coalesced float4 out = u + delta
    float* dS = (float*)&h1s[0][0];              // [64][68] f32 overlay (17.4 KB < 33.8 KB)
    {
        const int c = w * 16 + r;
        #pragma unroll
        for (int rt = 0; rt < 4; ++rt)
            #pragma unroll
            for (int j = 0; j < 4; ++j)
                dS[(rt * 16 + g * 4 + j) * 68 + c] = accOut[rt][j];
    }
    __syncthreads();
    float4* op = (float4*)(out + ((size_t)b * N_ + n0) * C_);
    #pragma unroll
    for (int i = 0; i < 4; ++i) {
        int idx = tid + 256 * i;
        int row = idx >> 4, c4 = idx & 15;
        float4 uv = up[idx];                     // L3-resident re-read
        float4 dv = *(float4*)&dS[row * 68 + c4 * 4];
        op[idx] = make_float4(uv.x + dv.x, uv.y + dv.y, uv.z + dv.z, uv.w + dv.w);
    }
}

extern "C" void kernel_launch(void* const* d_in, const int* in_sizes, int n_in,
                              void* d_out, int out_size, void* d_ws, size_t ws_size,
                              hipStream_t stream) {
    const float* u  = (const float*)d_in[0];
    const float* W1 = (const float*)d_in[1];
    const float* b1 = (const float*)d_in[2];
    const float* W2 = (const float*)d_in[3];
    const float* b2 = (const float*)d_in[4];
    const float* Wr = (const float*)d_in[5];
    const float* br = (const float*)d_in[6];
    float* out = (float*)d_out;

    char* ws = (char*)d_ws;
    float* pooled = (float*)ws;                                   // 8 KB
    unsigned short* W1T = (unsigned short*)(ws + 16384);          // 256 KB
    unsigned short* W2T = (unsigned short*)(ws + 16384 + 262144); // 256 KB

    hipMemsetAsync(pooled, 0, 2048 * sizeof(float), stream);
    prep_pool_kernel<<<1536, 256, 0, stream>>>(W1, W2, u, W1T, W2T, pooled);
    moe_main<<<dim3(64, 32), 256, 0, stream>>>(u, b1, b2, W1T, W2T, pooled, Wr, br, out);
}

// Round 4
// 167.293 us; speedup vs baseline: 1.1829x; 1.1478x over previous
//
#include <hip/hip_runtime.h>
#include <hip/hip_bf16.h>
#include <math.h>

#define B_ 32
#define N_ 4096
#define C_ 64
#define H_ 256
#define P_ 8
#define NPOOL 1024

typedef short bf16x8 __attribute__((ext_vector_type(8)));
typedef float f32x4 __attribute__((ext_vector_type(4)));

union BF8 { bf16x8 v; unsigned int w[4]; };

__device__ __forceinline__ unsigned short f2bf(float f) {
    union { float f; unsigned int u; } v; v.f = f;
    unsigned int r = v.u + 0x7FFFu + ((v.u >> 16) & 1u);
    return (unsigned short)(r >> 16);
}
__device__ __forceinline__ float bf2f(unsigned short h) {
    union { float f; unsigned int u; } v; v.u = ((unsigned int)h) << 16; return v.f;
}
__device__ __forceinline__ unsigned int pk_bf16(float lo, float hi) {
    unsigned int r;
    asm("v_cvt_pk_bf16_f32 %0, %1, %2" : "=v"(r) : "v"(lo), "v"(hi));
    return r;
}
// wk * gelu_tanh(x);  gelu = x*(1-rc), rc = 1/(exp2(y2)+1), y2 = 2*log2e*0.7978845608*(x+0.044715x^3)
__device__ __forceinline__ float gelu_w(float x, float wk) {
    float x2 = x * x;
    float y2 = x * fmaf(0.10294322f, x2, 2.30220772f);
    float e  = __builtin_amdgcn_exp2f(y2);
    float rc = __builtin_amdgcn_rcpf(e + 1.0f);
    float wx = wk * x;
    return fmaf(-wx, rc, wx);
}

// h-permutation: h = 32*(t>>1) + 8*(d>>2) + 4*(t&1) + (d&3)
__device__ __forceinline__ int hperm(int t, int d) {
    return ((t >> 1) << 5) + ((d >> 2) << 3) + ((t & 1) << 2) + (d & 3);
}

// ---------------- prep (W1P permuted, W2T, b1P) + pool + last-block router ----------------
// blocks 0..511: W1P[e][t*16+d][c] = bf16(W1[e][c][hperm(t,d)])
// blocks 512..1023: W2T[e][c][h] = bf16(W2[e][h][c])
// blocks 1024..1031: b1P[e][t*16+d] = bf16(b1[e][hperm(t,d)])
// blocks 1032..2055: pool partial sums (atomic) + last block computes router
__global__ void prep_pool(const float* __restrict__ W1, const float* __restrict__ W2,
                          const float* __restrict__ b1, const float* __restrict__ u,
                          const float* __restrict__ Wr, const float* __restrict__ br,
                          unsigned short* __restrict__ W1P, unsigned short* __restrict__ W2T,
                          unsigned short* __restrict__ b1P, float* __restrict__ pooled,
                          int* __restrict__ counter, float4* __restrict__ route) {
    int bid = blockIdx.x, tid = threadIdx.x;
    if (bid < 512) {
        int oi = bid * 256 + tid;
        int e = oi >> 14, rowP = (oi >> 6) & 255, c = oi & 63;
        int h = hperm(rowP >> 4, rowP & 15);
        W1P[oi] = f2bf(W1[(e << 14) + (c << 8) + h]);
        return;
    }
    if (bid < 1024) {
        int oi = (bid - 512) * 256 + tid;
        int e = oi >> 14, c = (oi >> 8) & 63, h = oi & 255;
        W2T[oi] = f2bf(W2[(e << 14) + (h << 6) + c]);
        return;
    }
    if (bid < 1032) {
        int oi = (bid - 1024) * 256 + tid;      // 0..2047
        int e = oi >> 8, idx = oi & 255;
        int h = hperm(idx >> 4, idx & 15);
        b1P[oi] = f2bf(b1[(e << 8) + h]);
        return;
    }
    // ---- pool ----
    int pb = bid - 1032;
    int b = pb >> 5, chunk = pb & 31;
    int c = tid & 63, rg = tid >> 6;
    const float* base = u + ((size_t)b * N_ + (size_t)chunk * 128) * C_;
    float s = 0.f;
    #pragma unroll 4
    for (int i = 0; i < 32; ++i) s += base[(i * 4 + rg) * C_ + c];
    __shared__ float red[4][64];
    __shared__ int isLast;
    __shared__ float lgAll[B_][P_];
    red[rg][c] = s;
    __syncthreads();
    if (tid < 64) {
        float t4 = red[0][tid] + red[1][tid] + red[2][tid] + red[3][tid];
        atomicAdd(&pooled[b * C_ + tid], t4);
        __threadfence();
    }
    __syncthreads();
    if (tid == 0) {
        int old = atomicAdd(counter, 1);
        isLast = (old == NPOOL - 1);
    }
    __syncthreads();
    if (!isLast) return;
    __threadfence();
    // ---- router (one block, 256 threads = 32 b x 8 p) ----
    {
        int rb = tid >> 3, p = tid & 7;
        const float* pb2 = pooled + rb * C_;
        float sacc = br[p];
        #pragma unroll
        for (int cc = 0; cc < C_; ++cc) {
            float pv = __hip_atomic_load(&pb2[cc], __ATOMIC_RELAXED, __HIP_MEMORY_SCOPE_AGENT);
            sacc += pv * (1.0f / N_) * Wr[cc * P_ + p];
        }
        lgAll[rb][p] = sacc;
    }
    __syncthreads();
    if (tid < B_) {
        float lg[P_];
        #pragma unroll
        for (int p = 0; p < P_; ++p) lg[p] = lgAll[tid][p];
        int i0 = 0;
        #pragma unroll
        for (int p = 1; p < P_; ++p) if (lg[p] > lg[i0]) i0 = p;   // strict >: lowest idx on tie
        int i1 = (i0 == 0) ? 1 : 0;
        #pragma unroll
        for (int p = 0; p < P_; ++p) if (p != i0 && lg[p] > lg[i1]) i1 = p;
        float e1 = __expf(lg[i1] - lg[i0]);
        float w0 = 1.f / (1.f + e1);
        route[tid] = make_float4(w0, e1 * w0, __int_as_float(i0), __int_as_float(i1));
    }
}

// ---------------- main MoE-MLP: no LDS, no barriers, independent waves ----------------
// grid 512 blocks x 256 thr; each wave owns 64 n-rows of one sample b.
// GEMM1 (swapped, h-permuted W1P) leaves h1 exactly in GEMM2's A-fragment layout.
__global__ __launch_bounds__(256, 2)
void moe_main(const float* __restrict__ u, const unsigned short* __restrict__ W1P,
              const unsigned short* __restrict__ W2T, const unsigned short* __restrict__ b1P,
              const float* __restrict__ b2, const float4* __restrict__ route,
              float* __restrict__ out) {
    const int tid = threadIdx.x;
    const int wv = tid >> 6, lane = tid & 63;
    const int r = lane & 15, g = lane >> 4;
    const int b = blockIdx.x >> 4;
    const int nslab = ((blockIdx.x & 15) << 2) + wv;
    const int n0 = nslab << 6;                       // 64 rows per wave

    float4 rd = route[b];
    const float wk2[2] = { rd.x, rd.y };
    const int eidx[2] = { __float_as_int(rd.z), __float_as_int(rd.w) };

    // ---- u B-fragments: ub[rt][ks] = u[n0+rt*16+r][ks*32+g*8 .. +8] as bf16x8
    const float* ubase = u + ((size_t)b * N_ + n0) * C_;
    bf16x8 ub[4][2];
    #pragma unroll
    for (int rt = 0; rt < 4; ++rt) {
        const float* rp = ubase + (rt * 16 + r) * C_;
        #pragma unroll
        for (int ks = 0; ks < 2; ++ks) {
            float4 lo = *(const float4*)(rp + ks * 32 + g * 8);
            float4 hi = *(const float4*)(rp + ks * 32 + g * 8 + 4);
            BF8 t;
            t.w[0] = pk_bf16(lo.x, lo.y); t.w[1] = pk_bf16(lo.z, lo.w);
            t.w[2] = pk_bf16(hi.x, hi.y); t.w[3] = pk_bf16(hi.z, hi.w);
            ub[rt][ks] = t.v;
        }
    }

    f32x4 acc2[4][4];                                // [ct][rt], spans both experts (wk folded in)
    #pragma unroll
    for (int ct = 0; ct < 4; ++ct)
        #pragma unroll
        for (int rt = 0; rt < 4; ++rt)
            #pragma unroll
            for (int q = 0; q < 4; ++q) acc2[ct][rt][q] = 0.f;

    for (int ke = 0; ke < 2; ++ke) {
        const int e = eidx[ke];
        const float wk = wk2[ke];
        const unsigned short* w1p = W1P + (e << 14);
        const unsigned short* w2t = W2T + (e << 14);
        const unsigned short* b1e = b1P + (e << 8);

        #pragma unroll
        for (int tp = 0; tp < 8; ++tp) {             // t-pair == kk of GEMM2
            // GEMM1: A = W1P rows (permuted h), B = u^T
            bf16x8 a1[2][2];
            #pragma unroll
            for (int tt = 0; tt < 2; ++tt)
                #pragma unroll
                for (int ks = 0; ks < 2; ++ks)
                    a1[tt][ks] = *(const bf16x8*)(w1p + ((tp * 32 + tt * 16 + r) << 6) + ks * 32 + g * 8);
            f32x4 acc1[2][4];
            #pragma unroll
            for (int tt = 0; tt < 2; ++tt)
                #pragma unroll
                for (int rt = 0; rt < 4; ++rt)
                    #pragma unroll
                    for (int q = 0; q < 4; ++q) acc1[tt][rt][q] = 0.f;
            #pragma unroll
            for (int ks = 0; ks < 2; ++ks)
                #pragma unroll
                for (int tt = 0; tt < 2; ++tt)
                    #pragma unroll
                    for (int rt = 0; rt < 4; ++rt)
                        acc1[tt][rt] = __builtin_amdgcn_mfma_f32_16x16x32_bf16(
                            a1[tt][ks], ub[rt][ks], acc1[tt][rt], 0, 0, 0);

            // bias + wk*gelu + pack -> GEMM2 A-fragments (no shuffle needed, by h-permutation)
            float bv[8];   // b1P[e][tp*32 + tt*16 + 4g + j]
            {
                const unsigned short* bp = b1e + tp * 32 + 4 * g;
                #pragma unroll
                for (int j = 0; j < 4; ++j) { bv[j] = bf2f(bp[j]); bv[4 + j] = bf2f(bp[16 + j]); }
            }
            bf16x8 a2[4];
            #pragma unroll
            for (int rt = 0; rt < 4; ++rt) {
                float gv[8];
                #pragma unroll
                for (int j = 0; j < 4; ++j) {
                    gv[j]     = gelu_w(acc1[0][rt][j] + bv[j],     wk);
                    gv[4 + j] = gelu_w(acc1[1][rt][j] + bv[4 + j], wk);
                }
                BF8 t;
                t.w[0] = pk_bf16(gv[0], gv[1]); t.w[1] = pk_bf16(gv[2], gv[3]);
                t.w[2] = pk_bf16(gv[4], gv[5]); t.w[3] = pk_bf16(gv[6], gv[7]);
                a2[rt] = t.v;
            }

            // GEMM2: B = W2T rows (plain), contract k = h in [tp*32, tp*32+32)
            bf16x8 b2f[4];
            #pragma unroll
            for (int ct = 0; ct < 4; ++ct)
                b2f[ct] = *(const bf16x8*)(w2t + ((ct * 16 + r) << 8) + tp * 32 + g * 8);
            #pragma unroll
            for (int ct = 0; ct < 4; ++ct)
                #pragma unroll
                for (int rt = 0; rt < 4; ++rt)
                    acc2[ct][rt] = __builtin_amdgcn_mfma_f32_16x16x32_bf16(
                        a2[rt], b2f[ct], acc2[ct][rt], 0, 0, 0);
        }
    }

    // ---- epilogue: out = u + acc2 + sum_e wk_e*b2_e   (residual re-read: L1/L2-hot)
    float bsum[4];
    #pragma unroll
    for (int ct = 0; ct < 4; ++ct) {
        int c = ct * 16 + r;
        bsum[ct] = wk2[0] * b2[eidx[0] * C_ + c] + wk2[1] * b2[eidx[1] * C_ + c];
    }
    float* obase = out + ((size_t)b * N_ + n0) * C_;
    #pragma unroll
    for (int rt = 0; rt < 4; ++rt)
        #pragma unroll
        for (int j = 0; j < 4; ++j) {
            int row = rt * 16 + 4 * g + j;
            #pragma unroll
            for (int ct = 0; ct < 4; ++ct) {
                int c = ct * 16 + r;
                obase[row * C_ + c] = ubase[row * C_ + c] + acc2[ct][rt][j] + bsum[ct];
            }
        }
}

extern "C" void kernel_launch(void* const* d_in, const int* in_sizes, int n_in,
                              void* d_out, int out_size, void* d_ws, size_t ws_size,
                              hipStream_t stream) {
    const float* u  = (const float*)d_in[0];
    const float* W1 = (const float*)d_in[1];
    const float* b1 = (const float*)d_in[2];
    const float* W2 = (const float*)d_in[3];
    const float* b2 = (const float*)d_in[4];
    const float* Wr = (const float*)d_in[5];
    const float* br = (const float*)d_in[6];
    float* out = (float*)d_out;

    char* ws = (char*)d_ws;
    float* pooled        = (float*)ws;                         // 8192 B
    int* counter         = (int*)(ws + 8192);                  // 64 B slot
    float4* route        = (float4*)(ws + 8256);               // 512 B
    unsigned short* b1P  = (unsigned short*)(ws + 8768);       // 4096 B
    unsigned short* W1P  = (unsigned short*)(ws + 16384);      // 256 KB
    unsigned short* W2T  = (unsigned short*)(ws + 16384 + 262144); // 256 KB  (end = 540672)

    hipMemsetAsync(ws, 0, 8256, stream);   // pooled + counter
    prep_pool<<<2056, 256, 0, stream>>>(W1, W2, b1, u, Wr, br, W1P, W2T, b1P, pooled, counter, route);
    moe_main<<<512, 256, 0, stream>>>(u, W1P, W2T, b1P, b2, route, out);
}